// Round 3
// baseline (215.701 us; speedup 1.0000x reference)
//
#include <hip/hip_runtime.h>
#include <stdint.h>

// Q2Linear: out = x @ (w*scale)^T.  M=1024, N=4096, K=4096, scale block=128.
// Pass 1: convert x (fp32) and w (int32 {-2..1} * per-block scale) to bf16
//         directly in MFMA *fragment order* in d_ws.
// Pass 2: barrier-free, LDS-free bf16 MFMA GEMM: each wave owns a 64x64 tile,
//         fragments are loaded as coalesced 1KB global_load_dwordx4 with
//         register double-buffering; 16 independent acc chains keep the MFMA
//         pipe full.  Fragment layout (validated round-2):
//           frag[id][lane] = src[row16 + (lane&15)][kp*32 + (lane>>4)*8 + 0..7]
//         stored flat: ((rowTile64*128 + kp)*4 + i)*512 + lane*8  (ushorts)

#define MM 1024
#define NN 4096
#define KK 4096

typedef __attribute__((ext_vector_type(8))) short short8;
typedef __attribute__((ext_vector_type(4))) float floatx4;
typedef __attribute__((ext_vector_type(4))) int intx4;
typedef __attribute__((ext_vector_type(8))) unsigned short ushortx8;

__device__ __forceinline__ unsigned short f2bf(float f) {
    union { float f; unsigned u; } v; v.f = f;
    return (unsigned short)((v.u + 0x7FFFu + ((v.u >> 16) & 1u)) >> 16);  // RNE
}

// ---- pass 1a: x fp32 -> bf16 fragments --------------------------------------
// thread t -> frag id g = t>>6 (i = g&3, kp = (g>>2)&127, mt = g>>9), lane = t&63
__global__ __launch_bounds__(256) void conv_x(const float* __restrict__ x,
                                              unsigned short* __restrict__ xb) {
    int t = blockIdx.x * 256 + threadIdx.x;
    int lane = t & 63, g = t >> 6;
    int i = g & 3, kp = (g >> 2) & 127, mt = g >> 9;
    int m = mt * 64 + i * 16 + (lane & 15);
    int k = kp * 32 + ((lane >> 4) << 3);
    const float* src = x + (size_t)m * KK + k;   // 32B per thread; wave covers full 128B lines
    floatx4 v0 = *(const floatx4*)src;
    floatx4 v1 = *(const floatx4*)(src + 4);
    ushortx8 h;
    h[0] = f2bf(v0[0]); h[1] = f2bf(v0[1]); h[2] = f2bf(v0[2]); h[3] = f2bf(v0[3]);
    h[4] = f2bf(v1[0]); h[5] = f2bf(v1[1]); h[6] = f2bf(v1[2]); h[7] = f2bf(v1[3]);
    *(ushortx8*)(xb + (size_t)t * 8) = h;        // fully coalesced 16B store
}

// ---- pass 1b: w int32 * scale -> bf16 fragments (scale folded once) ----------
__global__ __launch_bounds__(256) void conv_w(const int* __restrict__ wq,
                                              const float* __restrict__ scales,
                                              unsigned short* __restrict__ wb) {
    int t = blockIdx.x * 256 + threadIdx.x;
    int lane = t & 63, g = t >> 6;
    int j = g & 3, kp = (g >> 2) & 127, nt = g >> 9;
    int n = nt * 64 + j * 16 + (lane & 15);
    int k = kp * 32 + ((lane >> 4) << 3);
    const int* src = wq + (size_t)n * KK + k;
    float s = scales[n * (KK >> 7) + (k >> 7)];  // uniform over the thread's 8 elems
    intx4 w0 = *(const intx4*)src;
    intx4 w1 = *(const intx4*)(src + 4);
    ushortx8 h;
    h[0] = f2bf((float)w0[0] * s); h[1] = f2bf((float)w0[1] * s);
    h[2] = f2bf((float)w0[2] * s); h[3] = f2bf((float)w0[3] * s);
    h[4] = f2bf((float)w1[0] * s); h[5] = f2bf((float)w1[1] * s);
    h[6] = f2bf((float)w1[2] * s); h[7] = f2bf((float)w1[3] * s);
    *(ushortx8*)(wb + (size_t)t * 8) = h;
}

// ---- pass 2: barrier-free fragment-direct GEMM -------------------------------
__global__ __launch_bounds__(256) void q2_gemm(const unsigned short* __restrict__ xb,
                                               const unsigned short* __restrict__ wb,
                                               float* __restrict__ out) {
    const int tid  = threadIdx.x;
    const int lane = tid & 63;
    const int wave = tid >> 6;
    const int r16  = lane & 15;
    const int quad = lane >> 4;

    // 4 waves of a block share one n-tile (B frags L1-hit for 3 of 4 waves),
    // each wave a different m-tile.  grid = 64 nt * 4 mtg = 256 blocks.
    const int b  = blockIdx.x;
    const int nt = b >> 2;                 // 0..63
    const int mt = (b & 3) * 4 + wave;     // 0..15

    const unsigned short* pA = xb + (size_t)mt * 128 * 2048 + lane * 8;
    const unsigned short* pB = wb + (size_t)nt * 128 * 2048 + lane * 8;

    floatx4 acc[4][4];
#pragma unroll
    for (int i = 0; i < 4; ++i)
#pragma unroll
        for (int j = 0; j < 4; ++j) acc[i][j] = (floatx4){0.f, 0.f, 0.f, 0.f};

    short8 a0[4], b0[4], a1[4], b1[4];

#define LOADG(A, B, KP)                                                         \
    {                                                                           \
        const unsigned short* qa = pA + (size_t)(KP) * 2048;                    \
        const unsigned short* qb = pB + (size_t)(KP) * 2048;                    \
        _Pragma("unroll")                                                       \
        for (int i = 0; i < 4; ++i) {                                           \
            A[i] = *(const short8*)(qa + i * 512);                              \
            B[i] = *(const short8*)(qb + i * 512);                              \
        }                                                                       \
    }

#define MF(A, B)                                                                \
    {                                                                           \
        _Pragma("unroll")                                                       \
        for (int i = 0; i < 4; ++i)                                             \
            _Pragma("unroll")                                                   \
            for (int j = 0; j < 4; ++j)                                         \
                acc[i][j] = __builtin_amdgcn_mfma_f32_16x16x32_bf16(            \
                    A[i], B[j], acc[i][j], 0, 0, 0);                            \
    }

    LOADG(a0, b0, 0)
    for (int kp = 0; kp < 128; kp += 2) {
        LOADG(a1, b1, kp + 1)            // prefetch; MFMA below covers latency
        MF(a0, b0)
        LOADG(a0, b0, (kp + 2) & 127)    // &127: last iter wraps to valid mem, discarded
        MF(a1, b1)
    }

    // epilogue: C/D col = lane&15 (n), row = quad*4 + reg (m)
#pragma unroll
    for (int i = 0; i < 4; ++i) {
#pragma unroll
        for (int r = 0; r < 4; ++r) {
            int mg = mt * 64 + i * 16 + quad * 4 + r;
            float* orow = out + (size_t)mg * NN + nt * 64 + r16;
#pragma unroll
            for (int j = 0; j < 4; ++j) orow[j * 16] = acc[i][j][r];
        }
    }
#undef LOADG
#undef MF
}

extern "C" void kernel_launch(void* const* d_in, const int* in_sizes, int n_in,
                              void* d_out, int out_size, void* d_ws, size_t ws_size,
                              hipStream_t stream) {
    const float* x      = (const float*)d_in[0];
    const int*   wq     = (const int*)d_in[1];
    const float* scales = (const float*)d_in[2];
    float*       out    = (float*)d_out;

    unsigned short* xb = (unsigned short*)d_ws;                               // 8.4 MB
    unsigned short* wb = (unsigned short*)((char*)d_ws + (size_t)MM * KK * 2); // 33.6 MB

    conv_x<<<MM * KK / 8 / 256, 256, 0, stream>>>(x, xb);
    conv_w<<<NN * KK / 8 / 256, 256, 0, stream>>>(wq, scales, wb);
    q2_gemm<<<(MM / 64 / 4) * (NN / 64), 256, 0, stream>>>(xb, wb, out);
}

// Round 4
// 157.850 us; speedup vs baseline: 1.3665x; 1.3665x over previous
//
#include <hip/hip_runtime.h>
#include <stdint.h>

// Q2Linear int8 path.  out[m,n] = q[m] * sum_b s[n,b] * (i32 dot of xq[m,b*128..] . w[n,b*128..])
// Pass 1a: per-row quantize x -> i8 (q = rowmax/127), exact i8 w pass 1b.
// Pass 2: i8 MFMA GEMM (16x16x64), BK=128 = one scale block; i32 partials
//         scaled by s[n,b] in fp32 each slab; q[m] folded at epilogue.
// LDS machinery identical to round-2's verified bf16 kernel (128B rows,
// 16B-chunk XOR swizzle, global_load_lds width 16, zero bank conflicts).

#define MM 1024
#define NN 4096
#define KK 4096
#define BK 128   // bytes == elements (i8); one scale block per slab

typedef __attribute__((ext_vector_type(4))) int intx4;
typedef __attribute__((ext_vector_type(4))) float floatx4;

typedef const __attribute__((address_space(1))) void global_cvoid;
typedef __attribute__((address_space(3))) void lds_void;

// ---- pass 1a: per-row quantize x fp32 -> i8 ----------------------------------
__global__ __launch_bounds__(256) void quant_x(const float* __restrict__ x,
                                               char* __restrict__ xq,
                                               float* __restrict__ qrow) {
    const int m   = blockIdx.x;
    const int tid = threadIdx.x;
    const float* xr = x + (size_t)m * KK;
    floatx4 v[4];
    float amax = 0.f;
#pragma unroll
    for (int c = 0; c < 4; ++c) {
        v[c] = *(const floatx4*)(xr + (c * 256 + tid) * 4);
#pragma unroll
        for (int e = 0; e < 4; ++e) amax = fmaxf(amax, fabsf(v[c][e]));
    }
#pragma unroll
    for (int off = 32; off; off >>= 1) amax = fmaxf(amax, __shfl_down(amax, off));
    __shared__ float wmax[4];
    if ((tid & 63) == 0) wmax[tid >> 6] = amax;
    __syncthreads();
    amax = fmaxf(fmaxf(wmax[0], wmax[1]), fmaxf(wmax[2], wmax[3]));
    amax = fmaxf(amax, 1e-20f);
    const float qinv = 127.0f / amax;
    if (tid == 0) qrow[m] = amax / 127.0f;
#pragma unroll
    for (int c = 0; c < 4; ++c) {
        int p = 0;
#pragma unroll
        for (int e = 0; e < 4; ++e) {
            float r = rintf(v[c][e] * qinv);
            r = fminf(fmaxf(r, -127.f), 127.f);
            p |= ((int)r & 255) << (8 * e);
        }
        *(int*)(xq + (size_t)m * KK + (c * 256 + tid) * 4) = p;
    }
}

// ---- pass 1b: w int32 -> i8 (exact) ------------------------------------------
__global__ __launch_bounds__(256) void conv_w8(const int* __restrict__ wq,
                                               char* __restrict__ wb) {
    int t = blockIdx.x * 256 + threadIdx.x;  // 16 elems per thread
    const intx4* src = (const intx4*)wq + (size_t)t * 4;
    intx4 o;
#pragma unroll
    for (int c = 0; c < 4; ++c) {
        intx4 a = src[c];
        o[c] = (a[0] & 255) | ((a[1] & 255) << 8) | ((a[2] & 255) << 16) | (a[3] << 24);
    }
    *((intx4*)wb + t) = o;
}

// ---- pass 2: i8 MFMA GEMM ----------------------------------------------------
__global__ __launch_bounds__(256) void q8_gemm(const char* __restrict__ xq,
                                               const char* __restrict__ wb,
                                               const float* __restrict__ qrow,
                                               const float* __restrict__ scales,
                                               float* __restrict__ out) {
    __shared__ char As[2][128 * BK];   // 16 KB each
    __shared__ char Bs[2][128 * BK];
    __shared__ float Sl[32 * 128];     // scales transposed [b][n_local], 16 KB

    const int tid  = threadIdx.x;
    const int lane = tid & 63;
    const int wave = tid >> 6;
    const int wm   = (wave & 1) * 64;
    const int wn   = (wave >> 1) * 64;
    const int r16  = lane & 15;
    const int quad = lane >> 4;
    const int sw   = r16 & 7;

    // XCD pinning: bid&7 -> XCD; each XCD owns a 512-wide n-strip (2MB i8, L2-resident)
    const int bid = blockIdx.x;
    const int xcd = bid & 7, loc = bid >> 3;
    const int nT = xcd * 4 + (loc & 3);   // 0..31
    const int mT = loc >> 2;              // 0..7
    const int mBase = mT * 128, nBase = nT * 128;

    // staging address permute (identical to round 2, byte-for-byte)
    const int rg = lane >> 3;
    const int cs = (lane & 7) ^ rg;
    const char* gA = xq + (size_t)(mBase + wave * 32 + rg) * KK + cs * 16;
    const char* gB = wb + (size_t)(nBase + wave * 32 + rg) * KK + cs * 16;
    const int ldsRow = wave * 32;

    floatx4 facc[4][4];
#pragma unroll
    for (int i = 0; i < 4; ++i)
#pragma unroll
        for (int j = 0; j < 4; ++j) facc[i][j] = (floatx4){0.f, 0.f, 0.f, 0.f};

#define STAGE(BUF, SLAB)                                                        \
    {                                                                           \
        _Pragma("unroll")                                                       \
        for (int t = 0; t < 4; ++t) {                                           \
            __builtin_amdgcn_global_load_lds(                                   \
                (global_cvoid*)(gA + (size_t)(t * 8) * KK + (SLAB) * BK),       \
                (lds_void*)&As[BUF][(ldsRow + t * 8) * BK], 16, 0, 0);          \
            __builtin_amdgcn_global_load_lds(                                   \
                (global_cvoid*)(gB + (size_t)(t * 8) * KK + (SLAB) * BK),       \
                (lds_void*)&Bs[BUF][(ldsRow + t * 8) * BK], 16, 0, 0);          \
        }                                                                       \
    }

#define COMPUTE(BUF, SLAB)                                                      \
    {                                                                           \
        intx4 iacc[4][4];                                                       \
        _Pragma("unroll")                                                       \
        for (int kp = 0; kp < 2; ++kp) {                                        \
            intx4 av[4], bv[4];                                                 \
            _Pragma("unroll")                                                   \
            for (int i = 0; i < 4; ++i)                                         \
                av[i] = *(const intx4*)&As[BUF][(wm + i * 16 + r16) * BK +      \
                                               (((kp * 4 + quad) ^ sw) << 4)];  \
            _Pragma("unroll")                                                   \
            for (int j = 0; j < 4; ++j)                                         \
                bv[j] = *(const intx4*)&Bs[BUF][(wn + j * 16 + r16) * BK +      \
                                               (((kp * 4 + quad) ^ sw) << 4)];  \
            _Pragma("unroll")                                                   \
            for (int i = 0; i < 4; ++i)                                         \
                _Pragma("unroll")                                               \
                for (int j = 0; j < 4; ++j)                                     \
                    iacc[i][j] = __builtin_amdgcn_mfma_i32_16x16x64_i8(         \
                        av[i], bv[j], kp ? iacc[i][j] : (intx4){0, 0, 0, 0},    \
                        0, 0, 0);                                               \
        }                                                                       \
        float sf[4];                                                            \
        _Pragma("unroll")                                                       \
        for (int j = 0; j < 4; ++j) sf[j] = Sl[(SLAB) * 128 + wn + j * 16 + r16];\
        _Pragma("unroll")                                                       \
        for (int i = 0; i < 4; ++i)                                             \
            _Pragma("unroll")                                                   \
            for (int j = 0; j < 4; ++j)                                         \
                _Pragma("unroll")                                               \
                for (int r = 0; r < 4; ++r)                                     \
                    facc[i][j][r] += (float)iacc[i][j][r] * sf[j];              \
    }

    STAGE(0, 0)
    // stage scales (contiguous 16KB read, transposed into LDS)
    for (int t = tid; t < 4096; t += 256) {
        Sl[(t & 31) * 128 + (t >> 5)] = scales[(size_t)(nBase + (t >> 5)) * 32 + (t & 31)];
    }
    __syncthreads();

    const int NIT = KK / BK;  // 32
    for (int it = 0; it < NIT; it += 2) {
        if (it + 1 < NIT) STAGE(1, it + 1)
        COMPUTE(0, it)
        __syncthreads();
        if (it + 2 < NIT) STAGE(0, it + 2)
        COMPUTE(1, it + 1)
        __syncthreads();
    }

    // epilogue: C/D col = lane&15 (n), row = quad*4 + reg (m); fold q[m]
#pragma unroll
    for (int i = 0; i < 4; ++i) {
        floatx4 qv = *(const floatx4*)(qrow + mBase + wm + i * 16 + quad * 4);
#pragma unroll
        for (int r = 0; r < 4; ++r) {
            int mg = mBase + wm + i * 16 + quad * 4 + r;
            float* orow = out + (size_t)mg * NN + nBase + wn + r16;
#pragma unroll
            for (int j = 0; j < 4; ++j) orow[j * 16] = facc[i][j][r] * qv[r];
        }
    }
#undef STAGE
#undef COMPUTE
}

extern "C" void kernel_launch(void* const* d_in, const int* in_sizes, int n_in,
                              void* d_out, int out_size, void* d_ws, size_t ws_size,
                              hipStream_t stream) {
    const float* x      = (const float*)d_in[0];
    const int*   wq     = (const int*)d_in[1];
    const float* scales = (const float*)d_in[2];
    float*       out    = (float*)d_out;

    char*  xq   = (char*)d_ws;                                   // 4 MB
    float* qrow = (float*)((char*)d_ws + (size_t)MM * KK);       // 4 KB
    char*  wb   = (char*)d_ws + (size_t)MM * KK + 4096;          // 16.8 MB

    quant_x<<<MM, 256, 0, stream>>>(x, xq, qrow);
    conv_w8<<<(size_t)NN * KK / 16 / 256, 256, 0, stream>>>(wq, wb);
    q8_gemm<<<256, 256, 0, stream>>>(xq, wb, qrow, scales, out);
}